// Round 12
// baseline (335.891 us; speedup 1.0000x reference)
//
#include <hip/hip_runtime.h>
#include <cstdint>

typedef unsigned short ushort_t;
typedef __attribute__((ext_vector_type(4))) unsigned short ushort4_t;
typedef __attribute__((ext_vector_type(8))) unsigned short ushort8_t;
typedef __attribute__((ext_vector_type(8))) __bf16 bf16x8;
typedef __attribute__((ext_vector_type(4))) float f32x4;

constexpr int NB = 16;    // batch
constexpr int NC = 256;   // channels C (== E)
constexpr int NN = 4096;  // tokens N = H*W
constexpr int NP = 1024;  // region-proj channels = 2*R*heads
constexpr int NT = 512;   // heads * R (Rq columns of T)
constexpr int NO = 768;   // 3*E rows of Wqkv

static __device__ __forceinline__ ushort_t f2b(float f) {
  uint32_t u = __builtin_bit_cast(uint32_t, f);
  u += 0x7FFFu + ((u >> 16) & 1u);
  return (ushort_t)(u >> 16);
}
static __device__ __forceinline__ float b2f(ushort_t h) {
  return __builtin_bit_cast(float, (uint32_t)h << 16);
}
static __device__ __forceinline__ f32x4 mfma16(bf16x8 a, bf16x8 b, f32x4 c) {
  return __builtin_amdgcn_mfma_f32_16x16x32_bf16(a, b, c, 0, 0, 0);
}
typedef __attribute__((address_space(1))) const unsigned int guint;
typedef __attribute__((address_space(3))) unsigned int luint;
static __device__ __forceinline__ void glds16(const void* g, void* l) {
  __builtin_amdgcn_global_load_lds((guint*)g, (luint*)l, 16, 0, 0);
}

// ---------------------------------------------------------------------------
// Single-buffer 128x128 GEMM core: BK=64, LINEAR LDS (no swizzle — R12 A/B:
// XOR-permuted glds source suspected to break request coalescing; conflicts
// on reads are off the critical path in this 2-barrier structure).
// ---------------------------------------------------------------------------
template <int KITERS>
__device__ __forceinline__ void gemm_core_sb(const ushort_t* __restrict__ Asrc, size_t lda,
                                             const ushort_t* __restrict__ Bsrc, size_t ldb,
                                             ushort_t* SH, f32x4 (&acc)[4][4], int tid) {
  const int l = tid & 63, w = tid >> 6;
  const int fr = l & 15, kq = (l >> 4) * 8;
  const int rr = l >> 3;
  const int sc = (l & 7) << 3;  // LINEAR source col
  const int wm = (w >> 1) * 64, wn = (w & 1) * 64;
  ushort_t* As = SH;
  ushort_t* Bs = SH + 8192;
#pragma unroll 1
  for (int it = 0; it < KITERS; it++) {
    const size_t k0 = (size_t)it * 64;
#pragma unroll
    for (int i = 0; i < 4; i++) {
      const int row = i * 32 + w * 8 + rr;
      glds16(Asrc + (size_t)row * lda + k0 + sc, As + (i * 32 + w * 8) * 64);
      glds16(Bsrc + (size_t)row * ldb + k0 + sc, Bs + (i * 32 + w * 8) * 64);
    }
    __syncthreads();
#pragma unroll
    for (int ks = 0; ks < 2; ks++) {
      const int col = ks * 32 + kq;
      bf16x8 af[4], bf[4];
#pragma unroll
      for (int f = 0; f < 4; f++) {
        af[f] = *(const bf16x8*)&As[(wm + f * 16 + fr) * 64 + col];
        bf[f] = *(const bf16x8*)&Bs[(wn + f * 16 + fr) * 64 + col];
      }
#pragma unroll
      for (int fm = 0; fm < 4; fm++)
#pragma unroll
        for (int fn = 0; fn < 4; fn++)
          acc[fm][fn] = mfma16(af[fm], bf[fn], acc[fm][fn]);
    }
    __syncthreads();
  }
}

// ---------------------------------------------------------------------------
// K0: x (f32 [b][c][n]) -> xb (bf16 [b][c][n]) and xt (bf16 [b][n][c])
// ---------------------------------------------------------------------------
__global__ __launch_bounds__(256) void k0_cvt(const float* __restrict__ x,
                                              ushort_t* __restrict__ xb,
                                              ushort_t* __restrict__ xt) {
  __shared__ ushort_t tr[64][88];
  const int tid = threadIdx.x;
  const int n0 = blockIdx.x * 64, c0 = blockIdx.y * 64, b = blockIdx.z;
  const int cr = (tid >> 4) * 4;
  const int nc4 = (tid & 15) * 4;
#pragma unroll
  for (int i = 0; i < 4; i++) {
    size_t idx = ((size_t)b * NC + c0 + cr + i) * NN + n0 + nc4;
    float4 v = *(const float4*)(x + idx);
    ushort4_t o;
    o[0] = f2b(v.x); o[1] = f2b(v.y); o[2] = f2b(v.z); o[3] = f2b(v.w);
    *(ushort4_t*)(xb + idx) = o;
    tr[nc4 + 0][cr + i] = o[0];
    tr[nc4 + 1][cr + i] = o[1];
    tr[nc4 + 2][cr + i] = o[2];
    tr[nc4 + 3][cr + i] = o[3];
  }
  __syncthreads();
  const int nr = tid >> 2, cc0 = (tid & 3) * 16;
  size_t odx = ((size_t)b * NN + n0 + nr) * NC + c0 + cc0;
  *(ushort8_t*)(xt + odx) = *(const ushort8_t*)&tr[nr][cc0];
  *(ushort8_t*)(xt + odx + 8) = *(const ushort8_t*)&tr[nr][cc0 + 8];
}

// generic f32 -> bf16 (count multiple of 1024)
__global__ __launch_bounds__(256) void cvt_f2b_k(const float* __restrict__ src,
                                                 ushort_t* __restrict__ dst) {
  int i = (blockIdx.x * 256 + threadIdx.x) * 4;
  float4 v = *(const float4*)(src + i);
  ushort4_t o;
  o[0] = f2b(v.x); o[1] = f2b(v.y); o[2] = f2b(v.z); o[3] = f2b(v.w);
  *(ushort4_t*)(dst + i) = o;
}

// ---------------------------------------------------------------------------
// K1: P[b,p,n] = Wrb[p,:]·xt[b,n,:] + br[p]   (bf16 out, pre-softmax)
// 128x128, single-buffer core, 32 KB LDS, direct scalar stores.
// ---------------------------------------------------------------------------
__global__ __launch_bounds__(256) void k1_proj(const ushort_t* __restrict__ Wrb,
                                               const ushort_t* __restrict__ xt,
                                               const float* __restrict__ br,
                                               ushort_t* __restrict__ P) {
  __shared__ __align__(16) ushort_t SH[16384];  // 32 KB
  const int tid = threadIdx.x;
  const int ord = blockIdx.x;
  const int L = (ord & 7) * 512 + (ord >> 3);
  const int m0 = (L & 7) * 128;
  const int n0 = ((L >> 3) & 31) * 128;
  const int b = L >> 8;
  const int lane = tid & 63, w = tid >> 6;
  const int wm = (w >> 1) * 64, wn = (w & 1) * 64;
  f32x4 acc[4][4] = {};
  gemm_core_sb<4>(Wrb + (size_t)m0 * NC, NC,
                  xt + ((size_t)b * NN + n0) * NC, NC, SH, acc, tid);
  const int col = lane & 15, rb = (lane >> 4) * 4;
#pragma unroll
  for (int fm = 0; fm < 4; fm++)
#pragma unroll
    for (int rg = 0; rg < 4; rg++) {
      int row = m0 + wm + fm * 16 + rb + rg;
      float bias = br[row];
#pragma unroll
      for (int fn = 0; fn < 4; fn++) {
        int cc = n0 + wn + fn * 16 + col;
        P[((size_t)b * NP + row) * NN + cc] = f2b(acc[fm][fn][rg] + bias);
      }
    }
}

// ---------------------------------------------------------------------------
// K2: softmax over p (1024) per (b,n) column, in-place; rowsum partials.
// ---------------------------------------------------------------------------
__global__ __launch_bounds__(512) void k2_softmax(ushort_t* __restrict__ P,
                                                  float* __restrict__ sPpart) {
  __shared__ float red[64][64];
  __shared__ float Mf[64], If[64];
  const int tid = threadIdx.x;
  const int n0 = blockIdx.x * 64, b = blockIdx.y;
  const int cg = tid & 7, pg = tid >> 3;
  ushort_t* base = P + (size_t)b * NP * NN + n0 + cg * 8;

  ushort8_t v[16];
  float m[8];
#pragma unroll
  for (int j = 0; j < 8; j++) m[j] = -3.0e38f;
#pragma unroll
  for (int r = 0; r < 16; r++) {
    v[r] = *(const ushort8_t*)(base + (size_t)(pg * 16 + r) * NN);
#pragma unroll
    for (int j = 0; j < 8; j++) m[j] = fmaxf(m[j], b2f(v[r][j]));
  }
#pragma unroll
  for (int j = 0; j < 8; j++) red[pg][cg * 8 + j] = m[j];
  __syncthreads();
  if (tid < 64) {
    float M = -3.0e38f;
    for (int g = 0; g < 64; g++) M = fmaxf(M, red[g][tid]);
    Mf[tid] = M;
  }
  __syncthreads();
  float mj[8], s[8];
#pragma unroll
  for (int j = 0; j < 8; j++) { mj[j] = Mf[cg * 8 + j]; s[j] = 0.f; }
#pragma unroll
  for (int r = 0; r < 16; r++)
#pragma unroll
    for (int j = 0; j < 8; j++) s[j] += __expf(b2f(v[r][j]) - mj[j]);
#pragma unroll
  for (int j = 0; j < 8; j++) red[pg][cg * 8 + j] = s[j];
  __syncthreads();
  if (tid < 64) {
    float S = 0.f;
    for (int g = 0; g < 64; g++) S += red[g][tid];
    If[tid] = 1.f / S;
  }
  __syncthreads();
  float ij[8];
#pragma unroll
  for (int j = 0; j < 8; j++) ij[j] = If[cg * 8 + j];
#pragma unroll
  for (int r = 0; r < 16; r++) {
    int p = pg * 16 + r;
    ushort8_t o;
    float rs = 0.f;
#pragma unroll
    for (int j = 0; j < 8; j++) {
      float e = __expf(b2f(v[r][j]) - mj[j]) * ij[j];
      o[j] = f2b(e);
      rs += e;
    }
    *(ushort8_t*)(base + (size_t)p * NN) = o;
    rs += __shfl_xor(rs, 1, 64);
    rs += __shfl_xor(rs, 2, 64);
    rs += __shfl_xor(rs, 4, 64);
    if (cg == 0) sPpart[((size_t)blockIdx.x * NB + b) * NP + p] = rs;
  }
}

// K2r: sP[b,p] = sum over 64 n-blocks
__global__ __launch_bounds__(256) void k2r_reduce(const float* __restrict__ sPpart,
                                                  float* __restrict__ sP) {
  int idx = blockIdx.x * 256 + threadIdx.x;
  float s = 0.f;
#pragma unroll 8
  for (int bx = 0; bx < 64; bx++) s += sPpart[(size_t)bx * (NB * NP) + idx];
  sP[idx] = s;
}

// ---------------------------------------------------------------------------
// K3: XRbT[b][p][c] = f2b( sum_n xb[b,c,n]·P[b,p,n] )  (transposed bf16 out)
// Full K=4096, grid 256, double-buffered BK=64 pipeline, LINEAR LDS.
// ---------------------------------------------------------------------------
__global__ __launch_bounds__(256) void k3_pool(const ushort_t* __restrict__ xb,
                                               const ushort_t* __restrict__ P,
                                               ushort_t* __restrict__ XRbT) {
  __shared__ __align__(16) ushort_t SH[4 * 8192];  // 64 KB dbuf
  const int tid = threadIdx.x;
  const int ord = blockIdx.x;  // 256 blocks
  const int L = (ord & 7) * 32 + (ord >> 3);
  const int m0 = (L & 1) * 128;         // c
  const int n0 = ((L >> 1) & 7) * 128;  // p
  const int b = L >> 4;
  const int l = tid & 63, w = tid >> 6;
  const int fr = l & 15, kq = (l >> 4) * 8;
  const int rr = l >> 3;
  const int sc = (l & 7) << 3;  // LINEAR
  const int wm = (w >> 1) * 64, wn = (w & 1) * 64;
  const ushort_t* Asrc = xb + ((size_t)b * NC + m0) * NN;
  const ushort_t* Bsrc = P + ((size_t)b * NP + n0) * NN;
  f32x4 acc[4][4] = {};

  auto STAGE = [&](int bi, size_t k0) {
    ushort_t* Ad = SH + bi * 8192;
    ushort_t* Bd = SH + 16384 + bi * 8192;
#pragma unroll
    for (int i = 0; i < 4; i++) {
      const int row = i * 32 + w * 8 + rr;
      glds16(Asrc + (size_t)row * NN + k0 + sc, Ad + (i * 32 + w * 8) * 64);
      glds16(Bsrc + (size_t)row * NN + k0 + sc, Bd + (i * 32 + w * 8) * 64);
    }
  };

  STAGE(0, 0);
  __syncthreads();
  int cur = 0;
#pragma unroll 1
  for (int it = 0; it < 64; it++) {
    if (it + 1 < 64) STAGE(cur ^ 1, (size_t)(it + 1) * 64);
    const ushort_t* Ar = SH + cur * 8192;
    const ushort_t* Br = SH + 16384 + cur * 8192;
#pragma unroll
    for (int ks = 0; ks < 2; ks++) {
      const int col = ks * 32 + kq;
      bf16x8 af[4], bf[4];
#pragma unroll
      for (int f = 0; f < 4; f++) {
        af[f] = *(const bf16x8*)&Ar[(wm + f * 16 + fr) * 64 + col];
        bf[f] = *(const bf16x8*)&Br[(wn + f * 16 + fr) * 64 + col];
      }
#pragma unroll
      for (int fm = 0; fm < 4; fm++)
#pragma unroll
        for (int fn = 0; fn < 4; fn++)
          acc[fm][fn] = mfma16(af[fm], bf[fn], acc[fm][fn]);
    }
    __syncthreads();
    cur ^= 1;
  }
  // transposed epilogue: stage[p_local][c_local] stride 136, 2 passes
  const int colc = l & 15, rb = (l >> 4) * 4;
#pragma unroll
  for (int pp = 0; pp < 2; pp++) {
    if ((w & 1) == pp) {
#pragma unroll
      for (int fm = 0; fm < 4; fm++)
#pragma unroll
        for (int rg = 0; rg < 4; rg++) {
          const int cl = wm + fm * 16 + rb + rg;  // 0..127
#pragma unroll
          for (int fn = 0; fn < 4; fn++) {
            const int pl = fn * 16 + colc;  // 0..63
            SH[pl * 136 + cl] = f2b(acc[fm][fn][rg]);
          }
        }
    }
    __syncthreads();
    const int prow = tid >> 2, cch = (tid & 3) * 32;
    ushort_t* dst = XRbT + ((size_t)b * NP + n0 + pp * 64 + prow) * NC + m0 + cch;
    const ushort_t* s = &SH[prow * 136 + cch];
#pragma unroll
    for (int j = 0; j < 4; j++)
      *(ushort8_t*)(dst + j * 8) = *(const ushort8_t*)(s + j * 8);
    __syncthreads();
  }
}

// ---------------------------------------------------------------------------
// K4f: FUSED per-(b,h) QKV-projection + tiny attention + Wout fold -> Tmb.
// LINEAR LDS staging (no swizzle).
// ---------------------------------------------------------------------------
__global__ __launch_bounds__(256) void k4f_attn(const ushort_t* __restrict__ Wqkvb,
                                                const ushort_t* __restrict__ XRbT,
                                                const float* __restrict__ bqkv,
                                                const float* __restrict__ sP,
                                                const float* __restrict__ Wout,
                                                ushort_t* __restrict__ Tmb) {
  __shared__ __align__(16) char SHRAW[114688];  // 112 KB
  ushort_t* Aw = (ushort_t*)SHRAW;              // 96 x 256 (49152 B)
  ushort_t* Bw = (ushort_t*)(SHRAW + 49152);    // 128 x 256 (65536 B)
  float* qf = (float*)SHRAW;                    // reuse: 96 x 64 (24576 B)
  float* attn_sT = (float*)(SHRAW + 24576);     // 64 x 65 (16640 B)
  float* vals_s = (float*)(SHRAW + 41216);      // 32 x 64 (8192 B)
  const int b = blockIdx.x >> 3, h = blockIdx.x & 7;
  const int tid = threadIdx.x;
  const int l = tid & 63, w = tid >> 6;
  const ushort_t* Asrc = Wqkvb + (size_t)(h * 96) * NC;
  const ushort_t* Bsrc = XRbT + ((size_t)b * NP + h * 128) * NC;
  {
    const int r2 = l >> 5;
    const int oct = l & 31;
    const int scol = oct * 8;  // LINEAR
#pragma unroll
    for (int i = 0; i < 12; i++) {
      const int rbase = (i * 4 + w) * 2;
      glds16(Asrc + (size_t)(rbase + r2) * NC + scol, Aw + rbase * 256);
    }
#pragma unroll
    for (int i = 0; i < 16; i++) {
      const int rbase = (i * 4 + w) * 2;
      glds16(Bsrc + (size_t)(rbase + r2) * NC + scol, Bw + rbase * 256);
    }
  }
  __syncthreads();
  const int fr = l & 15, kq = (l >> 4) * 8;
  f32x4 acc[6][2] = {};
#pragma unroll
  for (int ks = 0; ks < 8; ks++) {
    const int col = ks * 32 + kq;
    bf16x8 bf[2];
#pragma unroll
    for (int f = 0; f < 2; f++)
      bf[f] = *(const bf16x8*)&Bw[(w * 32 + f * 16 + fr) * 256 + col];
#pragma unroll
    for (int fm = 0; fm < 6; fm++) {
      bf16x8 af = *(const bf16x8*)&Aw[(fm * 16 + fr) * 256 + col];
#pragma unroll
      for (int f = 0; f < 2; f++) acc[fm][f] = mfma16(af, bf[f], acc[fm][f]);
    }
  }
  __syncthreads();  // done reading Aw/Bw; regions reused for qf/attn
  {
    const int rb = (l >> 4) * 4;
    float spv[2];
#pragma unroll
    for (int f = 0; f < 2; f++)
      spv[f] = sP[(size_t)b * NP + h * 128 + w * 32 + f * 16 + fr];
    if (w < 2) {
#pragma unroll
      for (int fm = 0; fm < 2; fm++)
#pragma unroll
        for (int rg = 0; rg < 4; rg++) {
          const int row = fm * 16 + rb + rg;
          const float bq = bqkv[h * 96 + row];
#pragma unroll
          for (int f = 0; f < 2; f++)
            qf[row * 64 + w * 32 + f * 16 + fr] = acc[fm][f][rg] + bq * spv[f];
        }
    } else {
#pragma unroll
      for (int fm = 2; fm < 6; fm++)
#pragma unroll
        for (int rg = 0; rg < 4; rg++) {
          const int row = fm * 16 + rb + rg;
          const float bq = bqkv[h * 96 + row];
#pragma unroll
          for (int f = 0; f < 2; f++)
            qf[row * 64 + (w - 2) * 32 + f * 16 + fr] = acc[fm][f][rg] + bq * spv[f];
        }
    }
  }
  __syncthreads();
  const int lj = tid & 63;
  const int rq = tid >> 6;
  float kcol[32];
#pragma unroll
  for (int dd = 0; dd < 32; dd++) kcol[dd] = qf[(32 + dd) * 64 + lj];
  const float isc = 0.17677669529663687f;
#pragma unroll
  for (int r = 0; r < 16; r++) {
    int qi = r * 4 + rq;
    float a = 0.f;
#pragma unroll
    for (int dd = 0; dd < 32; dd++) a += qf[dd * 64 + qi] * kcol[dd];
    attn_sT[lj * 65 + qi] = a * isc;
  }
  __syncthreads();
  if (tid < 64) {
    float m = -3e38f;
    for (int k = 0; k < 64; k++) m = fmaxf(m, attn_sT[k * 65 + tid]);
    float s = 0.f;
    for (int k = 0; k < 64; k++) {
      float e = __expf(attn_sT[k * 65 + tid] - m);
      attn_sT[k * 65 + tid] = e;
      s += e;
    }
    float inv = 1.f / s;
    for (int k = 0; k < 64; k++) attn_sT[k * 65 + tid] *= inv;
  }
  __syncthreads();
  float acol[64];
#pragma unroll
  for (int k = 0; k < 64; k++) acol[k] = attn_sT[k * 65 + lj];
#pragma unroll
  for (int r = 0; r < 8; r++) {
    int dd = r * 4 + rq;
    float a = 0.f;
#pragma unroll
    for (int k = 0; k < 64; k++) a += qf[(64 + dd) * 64 + k] * acol[k];
    vals_s[dd * 64 + lj] = a;
  }
  __syncthreads();
  float vcol[32];
#pragma unroll
  for (int dd = 0; dd < 32; dd++) vcol[dd] = vals_s[dd * 64 + lj];
  for (int r = 0; r < 64; r++) {
    int c = r * 4 + rq;
    const float4* wp = (const float4*)(Wout + (size_t)c * NC + h * 32);
    float a = 0.f;
#pragma unroll
    for (int t = 0; t < 8; t++) {
      float4 ww = wp[t];
      a += ww.x * vcol[t * 4] + ww.y * vcol[t * 4 + 1] + ww.z * vcol[t * 4 + 2] +
           ww.w * vcol[t * 4 + 3];
    }
    Tmb[((size_t)b * NC + c) * NT + h * 64 + lj] = f2b(a);
  }
}

// ---------------------------------------------------------------------------
// K5: out = x + alpha*(Tmb·Pq + bout). A glds dbuf LINEAR (32KB); B reg-staged
// into SINGLE 18KB pad-72 LDS buffer. 51KB total -> 3 blocks/CU.
// ---------------------------------------------------------------------------
__global__ __launch_bounds__(256) void k5_out(const float* __restrict__ x,
                                              const ushort_t* __restrict__ P,
                                              const ushort_t* __restrict__ Tmb,
                                              const float* __restrict__ bout,
                                              const float* __restrict__ alpha,
                                              float* __restrict__ out) {
  __shared__ __align__(16) ushort_t Ash[2 * 8192];  // 32 KB
  __shared__ __align__(16) ushort_t Bsh[128 * 72];  // 18 KB single buffer
  const int tid = threadIdx.x;
  const int ord = blockIdx.x;
  const int L = (ord & 7) * 128 + (ord >> 3);
  const int m0 = (L & 1) * 128;
  const int n0 = ((L >> 1) & 31) * 128;
  const int b = L >> 6;
  const int lane = tid & 63, w = tid >> 6;
  const int wm = (w >> 1) * 64, wn = (w & 1) * 64;
  const int fr = lane & 15, kq = (lane >> 4) * 8;
  const int rr = lane >> 3;
  const int sc = (lane & 7) << 3;  // LINEAR
  const ushort_t* Asrc = Tmb + ((size_t)b * NC + m0) * NT;
  const int kg = tid >> 5, ng = (tid & 31) * 4;  // B stage: 8 k-rows x 4 n
  f32x4 acc[4][4] = {};
  ushort4_t bv[8];

  auto A_STAGE = [&](int bi, int k0) {
    ushort_t* Ad = Ash + bi * 8192;
#pragma unroll
    for (int i = 0; i < 4; i++) {
      const int row = i * 32 + w * 8 + rr;
      glds16(Asrc + (size_t)row * NT + k0 + sc, Ad + (i * 32 + w * 8) * 64);
    }
  };
  auto B_LOAD = [&](int k0) {
#pragma unroll
    for (int i = 0; i < 8; i++) {
      int hj = k0 + kg * 8 + i;
      int prow = ((hj >> 6) << 7) + (hj & 63);
      bv[i] = *(const ushort4_t*)(P + ((size_t)b * NP + prow) * NN + n0 + ng);
    }
  };
  auto B_WRITE = [&]() {
#pragma unroll
    for (int jj = 0; jj < 4; jj++) {
      ushort8_t pk;
#pragma unroll
      for (int i = 0; i < 8; i++) pk[i] = bv[i][jj];
      *(ushort8_t*)&Bsh[(ng + jj) * 72 + kg * 8] = pk;
    }
  };

  B_LOAD(0);
  A_STAGE(0, 0);
  B_WRITE();
  __syncthreads();
  int acur = 0;
#pragma unroll 1
  for (int it = 0; it < 8; it++) {
    if (it < 7) {
      B_LOAD((it + 1) * 64);
      A_STAGE(acur ^ 1, (it + 1) * 64);
    }
    const ushort_t* Ar = Ash + acur * 8192;
#pragma unroll
    for (int ks = 0; ks < 2; ks++) {
      const int col = ks * 32 + kq;
      bf16x8 af[4], bf[4];
#pragma unroll
      for (int f = 0; f < 4; f++) {
        af[f] = *(const bf16x8*)&Ar[(wm + f * 16 + fr) * 64 + col];
        bf[f] = *(const bf16x8*)&Bsh[(wn + f * 16 + fr) * 72 + col];
      }
#pragma unroll
      for (int fm = 0; fm < 4; fm++)
#pragma unroll
        for (int fn = 0; fn < 4; fn++)
          acc[fm][fn] = mfma16(af[fm], bf[fn], acc[fm][fn]);
    }
    __syncthreads();
    if (it < 7) {
      B_WRITE();
      __syncthreads();
    }
    acur ^= 1;
  }
  const float al = alpha[0];
  const int col = lane & 15, rb = (lane >> 4) * 4;
#pragma unroll
  for (int fm = 0; fm < 4; fm++)
#pragma unroll
    for (int rg = 0; rg < 4; rg++) {
      int row = m0 + wm + fm * 16 + rb + rg;
      float bias = bout[row];
#pragma unroll
      for (int fn = 0; fn < 4; fn++) {
        int cc = n0 + wn + fn * 16 + col;
        size_t idx = ((size_t)b * NC + row) * NN + cc;
        out[idx] = x[idx] + al * (acc[fm][fn][rg] + bias);
      }
    }
}

// ---------------------------------------------------------------------------
extern "C" void kernel_launch(void* const* d_in, const int* in_sizes, int n_in,
                              void* d_out, int out_size, void* d_ws, size_t ws_size,
                              hipStream_t stream) {
  const float* x = (const float*)d_in[0];
  const float* Wqkv = (const float*)d_in[1];
  const float* bqkv = (const float*)d_in[2];
  const float* Wr = (const float*)d_in[3];
  const float* br = (const float*)d_in[4];
  const float* Wout = (const float*)d_in[5];
  const float* bout = (const float*)d_in[6];
  const float* alpha = (const float*)d_in[7];
  float* out = (float*)d_out;

  char* ws = (char*)d_ws;
  ushort_t* P = (ushort_t*)ws;                    // [0, 134217728)
  ushort_t* xb = (ushort_t*)(ws + 134217728);     // 33.5MB (dead after k3)
  ushort_t* xt = (ushort_t*)(ws + 167772160);     // 33.5MB (dead after k1)
  ushort_t* XRbT = (ushort_t*)(ws + 167772160);   //   aliases xt: 8.4MB (k3+)
  ushort_t* Wrb = (ushort_t*)(ws + 201326592);    // 0.5MB
  float* sPpart = (float*)(ws + 201850880);       // 4.2MB (dead after k2r)
  ushort_t* Wqkvb = (ushort_t*)(ws + 201850880);  //   aliases sPpart: 0.4MB
  float* sP = (float*)(ws + 206045184);           // 64KB
  ushort_t* Tmb = (ushort_t*)(ws + 206110720);    // 4.2MB -> end 210305024

  k0_cvt<<<dim3(64, 4, 16), 256, 0, stream>>>(x, xb, xt);
  cvt_f2b_k<<<256, 256, 0, stream>>>(Wr, Wrb);
  k1_proj<<<4096, 256, 0, stream>>>(Wrb, xt, br, P);
  k2_softmax<<<dim3(64, 16), 512, 0, stream>>>(P, sPpart);
  k2r_reduce<<<64, 256, 0, stream>>>(sPpart, sP);
  cvt_f2b_k<<<192, 256, 0, stream>>>(Wqkv, Wqkvb);  // after k2r (aliases sPpart)
  k3_pool<<<256, 256, 0, stream>>>(xb, P, XRbT);    // writes into xt region (xt dead)
  k4f_attn<<<128, 256, 0, stream>>>(Wqkvb, XRbT, bqkv, sP, Wout, Tmb);
  k5_out<<<1024, 256, 0, stream>>>(x, P, Tmb, bout, alpha, out);
}